// Round 9
// baseline (223.471 us; speedup 1.0000x reference)
//
#include <hip/hip_runtime.h>

// GCN layer on MI355X — round 18: in-place csr -> fused pipeline fits 32.8MB.
// r17 was neutral: K2's inner loops were never the mass. The ~157us "rest"
// is STAGE SERIALIZATION — and tier-1 fusion (scatter || linear in one
// launch) likely never ran: it needed 39-45MB ws vs the proven 32.8MB.
// Fix: K3 writes csr IN PLACE over ebuf (per-bucket segment fully read into
// LDS before copy-out; segments disjoint; CAP=12288 = +76sigma, overflow
// impossible for random edge_index). NEED drops to 32.44MB -> fused K2
// always runs. Dispatches: memset, prep_hist, scatter_linear(fused),
// bucket_to_csr, gather. Gather (r16, 64.7us) untouched.
//   M1:  memsetAsync(bhist+gcurz, 0, 2KB)
//   K1 prep_hist:      Wsw swizzle + BN consts FUSED with bucket histogram
//   K2 scatter_linear: bucket_scatter (391, packed ebuf) FUSED with
//                      linear_mfma (1563, Wsw+x in LDS) — overlapped pipes.
//   K3 bucket_to_csr:  1024 threads/block; csr ALIASES ebuf (in-place).
//   K4 gather_bn_relu: full-row e4xc16 dwordx4 (64.7us proven).
// mean(h[src]) = mean(x[src])@W + b (linearity); deg=0 -> sum=0 -> relu(sh).

#define NN 100000
#define NE 1600000
#define CC 128
#define BN_EPS 1e-5f
#define LBLK 1563     // ceil(NN/64) linear blocks
#define LSTR 136      // LDS row stride in bf16 (128 + 8 pad)
#define NBUK 256      // dst buckets
#define DPB 391       // dsts per bucket (256*391 = 100096 >= NN)
#define ACH 4096      // edges per scatter block
#define ABLK 391      // ceil(NE/ACH)
#define CAP 12288     // to_csr LDS segment capacity (mean 6250, +76 sigma)
#define GNB 64        // nodes per gather block
#define CAP2 1536     // gather csr LDS cap (mean 1024, sd 32: +16sigma)

typedef __attribute__((ext_vector_type(8))) short bf16x8;
typedef __attribute__((ext_vector_type(4))) float f32x4;

static __device__ __forceinline__ short f2bf(float f) {
  union { float f; unsigned u; } v; v.f = f;
  unsigned r = (v.u + 0x7FFF + ((v.u >> 16) & 1)) >> 16;  // RNE
  return (short)r;
}
static __device__ __forceinline__ float bflo(unsigned p) {
  return __uint_as_float(p << 16);
}
static __device__ __forceinline__ float bfhi(unsigned p) {
  return __uint_as_float(p & 0xffff0000u);
}

// 256-wide Hillis-Steele scan in LDS; leaves a[] exclusive, returns excl[t].
// (256-thread blocks only.)
static __device__ __forceinline__ int excl_scan256(int* a, int t, int v) {
  a[t] = v;
  __syncthreads();
  for (int d = 1; d < 256; d <<= 1) {
    const int x = (t >= d) ? a[t - d] : 0;
    __syncthreads();
    a[t] += x;
    __syncthreads();
  }
  const int incl = a[t];
  __syncthreads();
  a[t] = incl - v;
  __syncthreads();
  return incl - v;
}

// ---------------------------------------------------------------------------
// K1: prep (Wsw swizzle, col-permuted so D-lane m holds natural cols m*8..+7;
// BN scale/shift + bias) on blocks 0-63, bucket histogram on all 391 blocks.
// bhist pre-zeroed by the M1 memset.
// ---------------------------------------------------------------------------
__global__ __launch_bounds__(256) void prep_hist(
    const float* __restrict__ W, const float* __restrict__ bias,
    const float* __restrict__ gamma, const float* __restrict__ beta,
    const float* __restrict__ rmean, const float* __restrict__ rvar,
    const int* __restrict__ ei, short* __restrict__ Wsw,
    float* __restrict__ scsh, int* __restrict__ bhist) {
  __shared__ int lh[NBUK];
  const int t = threadIdx.x;
  const int i = blockIdx.x * 256 + t;
  if (i < CC * CC) {
    const int k = i >> 7, n = i & 127;
    const int nt = n & 7, m = n >> 3;
    const int kb = k >> 5, q = (k >> 3) & 3, j = k & 7;
    Wsw[(size_t)(((nt * 4 + kb) * 64 + (m + 16 * q)) * 8 + j)] = f2bf(W[i]);
  }
  if (i < CC) {
    const float sc = gamma[i] * rsqrtf(rvar[i] + BN_EPS);
    scsh[i] = sc;
    scsh[CC + i] = beta[i] - rmean[i] * sc;
    scsh[2 * CC + i] = bias[i];
  }
  lh[t] = 0;
  __syncthreads();
  const int e0 = blockIdx.x * ACH;
  const int e1 = min(NE, e0 + ACH);
  for (int e = e0 + t; e < e1; e += 256) atomicAdd(&lh[ei[NE + e] / DPB], 1);
  __syncthreads();
  if (lh[t]) atomicAdd(&bhist[t], lh[t]);
}

// ---------------------------------------------------------------------------
// K2: blocks [0,scat): bucket_scatter — chunk-sort 4096 edges by bucket in
// LDS, reserve contiguous global runs, write PACKED ebuf ((src<<9)|dstlocal)
// coalesced. blocks [scat,..): linear_mfma — h = bf16(x@W+b): x staged to
// LDS bf16, Wsw staged to LDS once, MFMA, direct row-major stores.
// Manual smem union: scatter 37.9KB | linear 49.4KB.
// ---------------------------------------------------------------------------
__global__ __launch_bounds__(256) void scatter_linear(
    const int* __restrict__ ei, const int* __restrict__ bhist,
    int* __restrict__ gcurz, int* __restrict__ ebuf,
    const float* __restrict__ x, const short* __restrict__ Wsw,
    const float* __restrict__ scsh, short* __restrict__ hout,
    int scat) {
  __shared__ __align__(16) char smem[50176];
  const int t = threadIdx.x;

  if (blockIdx.x < scat) {
    // ----- scatter role -----
    int2* sorted = (int2*)smem;                 // 32768
    int*  gsc    = (int*)(smem + 32768);        // +1024
    int*  lh     = (int*)(smem + 33792);
    int*  lex    = (int*)(smem + 34816);
    int*  rb     = (int*)(smem + 35840);
    int*  lc     = (int*)(smem + 36864);        // end 37888
    const int e0 = blockIdx.x * ACH;
    const int e1 = min(NE, e0 + ACH);
    const int gbase = excl_scan256(gsc, t, bhist[t]);
    lh[t] = 0;
    __syncthreads();
    for (int e = e0 + t; e < e1; e += 256) atomicAdd(&lh[ei[NE + e] / DPB], 1);
    __syncthreads();
    const int vh = lh[t];
    const int lbase = excl_scan256(lex, t, vh);
    lc[t] = lbase;
    if (vh > 0) rb[t] = gbase + atomicAdd(&gcurz[t], vh);
    __syncthreads();
    for (int e = e0 + t; e < e1; e += 256) {
      const int src = ei[e], dst = ei[NE + e];
      const int p = atomicAdd(&lc[dst / DPB], 1);
      sorted[p] = make_int2(src, dst);
    }
    __syncthreads();
    const int n = e1 - e0;
    for (int i = t; i < n; i += 256) {
      const int2 v = sorted[i];
      const int b = v.y / DPB;
      ebuf[rb[b] + (i - lex[b])] = (v.x << 9) | (v.y - b * DPB);
    }
    return;
  }

  // ----- linear role -----
  short* lsA = (short*)smem;            // 64*LSTR*2 = 17408
  short* lsW = (short*)(smem + 17408);  // 32768 -> end 50176
  const int n0 = (blockIdx.x - scat) * 64;

#pragma unroll
  for (int j = 0; j < 8; ++j) {
    const int idx = j * 256 + t;
    const int row = idx >> 5, kc4 = idx & 31;
    float4 v = make_float4(0.f, 0.f, 0.f, 0.f);
    if (n0 + row < NN) v = *(const float4*)(x + (size_t)(n0 + row) * CC + kc4 * 4);
    short4 sv;
    sv.x = f2bf(v.x); sv.y = f2bf(v.y); sv.z = f2bf(v.z); sv.w = f2bf(v.w);
    *(short4*)(lsA + row * LSTR + kc4 * 4) = sv;
  }
  // stage Wsw (32KB) once per block: 8 x bf16x8 per thread, coalesced
#pragma unroll
  for (int j = 0; j < 8; ++j) {
    const int idx = j * 256 + t;
    *(bf16x8*)(lsW + (size_t)idx * 8) = *(const bf16x8*)(Wsw + (size_t)idx * 8);
  }
  __syncthreads();

  const int wave = t >> 6, lane = t & 63;
  const int quad = lane >> 4, m = lane & 15;
  const int rowbase = n0 + wave * 16;

  f32x4 acc[8];
#pragma unroll
  for (int nt = 0; nt < 8; ++nt) acc[nt] = (f32x4){0.f, 0.f, 0.f, 0.f};

#pragma unroll
  for (int kb = 0; kb < 4; ++kb) {
    const bf16x8 a =
        *(const bf16x8*)(lsA + (wave * 16 + m) * LSTR + kb * 32 + quad * 8);
#pragma unroll
    for (int nt = 0; nt < 8; ++nt) {
      const bf16x8 bb = *(const bf16x8*)(lsW + (size_t)(((nt * 4 + kb) * 64 + lane) * 8));
      acc[nt] = __builtin_amdgcn_mfma_f32_16x16x32_bf16(a, bb, acc[nt], 0, 0, 0);
    }
  }

  const float4 b0 = *(const float4*)(scsh + 2 * CC + m * 8);
  const float4 b1 = *(const float4*)(scsh + 2 * CC + m * 8 + 4);
  const float bv[8] = {b0.x, b0.y, b0.z, b0.w, b1.x, b1.y, b1.z, b1.w};

#pragma unroll
  for (int reg = 0; reg < 4; ++reg) {
    const int R = rowbase + quad * 4 + reg;
    if (R >= NN) continue;
    bf16x8 hv;
#pragma unroll
    for (int nt = 0; nt < 8; ++nt) hv[nt] = f2bf(acc[nt][reg] + bv[nt]);
    *(bf16x8*)(hout + (size_t)R * CC + m * 8) = hv;
  }
}

// ---------------------------------------------------------------------------
// K3: one 1024-thread block per bucket, packed ebuf. csr MAY ALIAS ebuf:
// all reads of the block's segment (histogram pass + LDS-scatter pass)
// complete before the copy-out writes; segments are disjoint across blocks.
// seglen > CAP is +76sigma for random edge_index — cannot occur.
// ---------------------------------------------------------------------------
__global__ __launch_bounds__(1024) void bucket_to_csr(
    const int* __restrict__ ebuf, const int* __restrict__ bhist,
    int* __restrict__ off, int* __restrict__ csr) {
  __shared__ int gs[NBUK];
  __shared__ int dh[512];
  __shared__ int s[512];
  __shared__ int lcur[512];
  __shared__ int lcsr[CAP];  // 48 KB
  const int b = blockIdx.x, t = threadIdx.x;

  if (t < NBUK) gs[t] = bhist[t];
  __syncthreads();
  for (int d = 1; d < NBUK; d <<= 1) {
    int a0 = 0;
    if (t < NBUK && t >= d) a0 = gs[t - d];
    __syncthreads();
    if (t < NBUK) gs[t] += a0;
    __syncthreads();
  }
  const int seglen = bhist[b];
  const int segbase = gs[b] - seglen;
  const int lo = b * DPB;
  const int hi = min(NN, lo + DPB);
  const int nd = hi - lo;
  const int* eb = ebuf + segbase;

  if (t < 512) dh[t] = 0;
  __syncthreads();
  for (int i = t; i < seglen; i += 1024) atomicAdd(&dh[eb[i] & 511], 1);
  __syncthreads();

  if (t < 512) s[t] = dh[t];
  __syncthreads();
  for (int d = 1; d < 512; d <<= 1) {
    int a0 = 0;
    if (t < 512 && t >= d) a0 = s[t - d];
    __syncthreads();
    if (t < 512) s[t] += a0;
    __syncthreads();
  }
  if (t < 512) lcur[t] = s[t] - dh[t];  // exclusive
  if (t < nd) off[lo + t] = segbase + (s[t] - dh[t]);
  if (b == NBUK - 1 && t == 0) off[NN] = NE;
  __syncthreads();

  if (seglen <= CAP) {
    for (int i = t; i < seglen; i += 1024) {
      const int e = eb[i];
      const int p = atomicAdd(&lcur[e & 511], 1);
      lcsr[p] = (int)((unsigned)e >> 9);
    }
    __syncthreads();  // all segment reads done -> in-place write is safe
    for (int i = t; i < seglen; i += 1024) csr[segbase + i] = lcsr[i];
  } else {
    // unreachable for random inputs (+76 sigma); non-aliased-safe fallback
    for (int i = t; i < seglen; i += 1024) {
      const int e = eb[i];
      const int p = atomicAdd(&lcur[e & 511], 1);
      csr[segbase + p] = (int)((unsigned)e >> 9);
    }
  }
}

// ---------------------------------------------------------------------------
// K4: full-row e4xc16 gather (64.7us proven). Block = 64 nodes; loff + csr
// segment staged in LDS. Wave = one node at a time; lane = (e4 = lane>>4,
// c16 = lane&15). One dwordx4 = 4 edges x 256B rows; csr via ds_read;
// epilogue shfl_xor(16,32) + BN on e4==0 lanes.
// ---------------------------------------------------------------------------
__global__ __launch_bounds__(256) void gather_bn_relu(
    const short* __restrict__ h, const int* __restrict__ off,
    const int* __restrict__ csr, const float* __restrict__ scsh,
    float* __restrict__ out) {
  __shared__ int loff[GNB + 1];
  __shared__ int lcsr[CAP2];  // 6 KB
  const int nb0 = blockIdx.x * GNB;
  const int t = threadIdx.x;
  const int nnb = min(GNB, NN - nb0);

  for (int i = t; i <= nnb; i += 256) loff[i] = off[nb0 + i];
  __syncthreads();
  const int s0 = loff[0];
  const int seglen = loff[nnb] - s0;
  const int stg = min(seglen, CAP2);
  for (int i = t; i < stg; i += 256) lcsr[i] = csr[s0 + i];
  __syncthreads();

  const int wave = t >> 6, lane = t & 63;
  const int e4 = lane >> 4;    // edge slot 0..3
  const int c16 = lane & 15;   // col block: natural cols c16*8..+7
  const float4 sc0 = *(const float4*)(scsh + c16 * 8);
  const float4 sc1 = *(const float4*)(scsh + c16 * 8 + 4);
  const float4 sh0 = *(const float4*)(scsh + CC + c16 * 8);
  const float4 sh1 = *(const float4*)(scsh + CC + c16 * 8 + 4);

  const int lEnd = min(nnb, wave * 16 + 16);
  const bool inl = (seglen <= CAP2);
  for (int l = wave * 16; l < lEnd; ++l) {
    const int s = inl ? loff[l] - s0 : loff[l];
    const int e = inl ? loff[l + 1] - s0 : loff[l + 1];
    float a0 = 0.f, a1 = 0.f, a2 = 0.f, a3 = 0.f;
    float a4 = 0.f, a5 = 0.f, a6 = 0.f, a7 = 0.f;
    int i = s + e4;
    for (; i + 4 < e; i += 8) {
      const int q0 = inl ? lcsr[i] : csr[i];
      const int q1 = inl ? lcsr[i + 4] : csr[i + 4];
      const uint4 p0 = *(const uint4*)(h + (size_t)q0 * CC + c16 * 8);
      const uint4 p1 = *(const uint4*)(h + (size_t)q1 * CC + c16 * 8);
      a0 += bflo(p0.x) + bflo(p1.x); a1 += bfhi(p0.x) + bfhi(p1.x);
      a2 += bflo(p0.y) + bflo(p1.y); a3 += bfhi(p0.y) + bfhi(p1.y);
      a4 += bflo(p0.z) + bflo(p1.z); a5 += bfhi(p0.z) + bfhi(p1.z);
      a6 += bflo(p0.w) + bflo(p1.w); a7 += bfhi(p0.w) + bfhi(p1.w);
    }
    if (i < e) {
      const int q = inl ? lcsr[i] : csr[i];
      const uint4 p = *(const uint4*)(h + (size_t)q * CC + c16 * 8);
      a0 += bflo(p.x); a1 += bfhi(p.x);
      a2 += bflo(p.y); a3 += bfhi(p.y);
      a4 += bflo(p.z); a5 += bfhi(p.z);
      a6 += bflo(p.w); a7 += bfhi(p.w);
    }
    // reduce across the 4 e4 groups (lane bits 4,5)
    a0 += __shfl_xor(a0, 16); a1 += __shfl_xor(a1, 16);
    a2 += __shfl_xor(a2, 16); a3 += __shfl_xor(a3, 16);
    a4 += __shfl_xor(a4, 16); a5 += __shfl_xor(a5, 16);
    a6 += __shfl_xor(a6, 16); a7 += __shfl_xor(a7, 16);
    a0 += __shfl_xor(a0, 32); a1 += __shfl_xor(a1, 32);
    a2 += __shfl_xor(a2, 32); a3 += __shfl_xor(a3, 32);
    a4 += __shfl_xor(a4, 32); a5 += __shfl_xor(a5, 32);
    a6 += __shfl_xor(a6, 32); a7 += __shfl_xor(a7, 32);
    if (e4 == 0) {
      const float inv = (e > s) ? 1.0f / (float)(e - s) : 0.0f;
      float4 o0, o1;
      o0.x = fmaxf(0.f, a0 * inv * sc0.x + sh0.x);
      o0.y = fmaxf(0.f, a1 * inv * sc0.y + sh0.y);
      o0.z = fmaxf(0.f, a2 * inv * sc0.z + sh0.z);
      o0.w = fmaxf(0.f, a3 * inv * sc0.w + sh0.w);
      o1.x = fmaxf(0.f, a4 * inv * sc1.x + sh1.x);
      o1.y = fmaxf(0.f, a5 * inv * sc1.y + sh1.y);
      o1.z = fmaxf(0.f, a6 * inv * sc1.z + sh1.z);
      o1.w = fmaxf(0.f, a7 * inv * sc1.w + sh1.w);
      float* op = out + (size_t)(nb0 + l) * CC + c16 * 8;
      *(float4*)op = o0;
      *(float4*)(op + 4) = o1;
    }
  }
}

// ---------------------------------------------------------------------------
// Fallback (small ws): atomic scatter + fp32 vector GEMM.
// ---------------------------------------------------------------------------
__global__ __launch_bounds__(256) void edge_scatter(
    const float* __restrict__ x, const int* __restrict__ ei,
    float* __restrict__ sums, int* __restrict__ cnt) {
  int gt = blockIdx.x * 256 + threadIdx.x;
  int e = gt >> 5;
  int sub = gt & 31;
  if (e >= NE) return;
  int src = ei[e];
  int dst = ei[NE + e];
  const float4 v = *(const float4*)(x + (size_t)src * CC + sub * 4);
  float* o = sums + (size_t)dst * CC + sub * 4;
  unsafeAtomicAdd(o + 0, v.x);
  unsafeAtomicAdd(o + 1, v.y);
  unsafeAtomicAdd(o + 2, v.z);
  unsafeAtomicAdd(o + 3, v.w);
  if (sub == 0) atomicAdd(cnt + dst, 1);
}

__global__ __launch_bounds__(256) void gemm_bn_relu_fb(
    float* buf, const float* __restrict__ W, const float* __restrict__ bias,
    const float* __restrict__ gamma, const float* __restrict__ beta,
    const float* __restrict__ rmean, const float* __restrict__ rvar,
    const int* __restrict__ cnt) {
  __shared__ float xsT[CC][65];
  const int t = threadIdx.x;
  const int n0 = blockIdx.x * 64;
  for (int j = 0; j < 8; ++j) {
    int i = t + 256 * j;
    int row = i >> 5;
    int ko = (i & 31) * 4;
    float4 v = make_float4(0.f, 0.f, 0.f, 0.f);
    if (n0 + row < NN) v = *(const float4*)(buf + (size_t)(n0 + row) * CC + ko);
    xsT[ko + 0][row] = v.x;
    xsT[ko + 1][row] = v.y;
    xsT[ko + 2][row] = v.z;
    xsT[ko + 3][row] = v.w;
  }
  __syncthreads();
  const int cg = t & 31;
  const int ng8 = (t >> 5) * 8;
  float acc[8][4];
#pragma unroll
  for (int j = 0; j < 8; ++j)
#pragma unroll
    for (int c = 0; c < 4; ++c) acc[j][c] = 0.f;
#pragma unroll 8
  for (int k = 0; k < CC; ++k) {
    const float4 wv = *(const float4*)(W + k * CC + cg * 4);
#pragma unroll
    for (int j = 0; j < 8; ++j) {
      const float xv = xsT[k][ng8 + j];
      acc[j][0] = fmaf(xv, wv.x, acc[j][0]);
      acc[j][1] = fmaf(xv, wv.y, acc[j][1]);
      acc[j][2] = fmaf(xv, wv.z, acc[j][2]);
      acc[j][3] = fmaf(xv, wv.w, acc[j][3]);
    }
  }
  const float4 bb = *(const float4*)(bias + cg * 4);
  const float4 gg = *(const float4*)(gamma + cg * 4);
  const float4 bt = *(const float4*)(beta + cg * 4);
  const float4 mu = *(const float4*)(rmean + cg * 4);
  const float4 vr = *(const float4*)(rvar + cg * 4);
  float sc[4], sh[4];
  sc[0] = gg.x * rsqrtf(vr.x + BN_EPS);
  sc[1] = gg.y * rsqrtf(vr.y + BN_EPS);
  sc[2] = gg.z * rsqrtf(vr.z + BN_EPS);
  sc[3] = gg.w * rsqrtf(vr.w + BN_EPS);
  sh[0] = bt.x - mu.x * sc[0];
  sh[1] = bt.y - mu.y * sc[1];
  sh[2] = bt.z - mu.z * sc[2];
  sh[3] = bt.w - mu.w * sc[3];
#pragma unroll
  for (int j = 0; j < 8; ++j) {
    const int n = n0 + ng8 + j;
    if (n >= NN) continue;
    const int cn = cnt[n];
    const float inv = cn > 0 ? 1.0f / (float)cn : 0.0f;
    const float bsel = cn > 0 ? 1.0f : 0.0f;
    float4 o;
    o.x = fmaxf(0.f, (acc[j][0] * inv + bsel * bb.x) * sc[0] + sh[0]);
    o.y = fmaxf(0.f, (acc[j][1] * inv + bsel * bb.y) * sc[1] + sh[1]);
    o.z = fmaxf(0.f, (acc[j][2] * inv + bsel * bb.z) * sc[2] + sh[2]);
    o.w = fmaxf(0.f, (acc[j][3] * inv + bsel * bb.w) * sc[3] + sh[3]);
    *(float4*)(buf + (size_t)n * CC + cg * 4) = o;
  }
}

extern "C" void kernel_launch(void* const* d_in, const int* in_sizes, int n_in,
                              void* d_out, int out_size, void* d_ws, size_t ws_size,
                              hipStream_t stream) {
  const float* x     = (const float*)d_in[0];
  const int*   ei    = (const int*)d_in[1];
  const float* W     = (const float*)d_in[2];
  const float* bias  = (const float*)d_in[3];
  const float* gamma = (const float*)d_in[4];
  const float* beta  = (const float*)d_in[5];
  const float* rmean = (const float*)d_in[6];
  const float* rvar  = (const float*)d_in[7];
  float* out = (float*)d_out;

  // ws layout (bytes):
  //   off[NN+1] | bhist[256] | gcurz[256] (contiguous -> one 2KB memset)
  //   | scsh[384f] | Wsw[16384 bf16] | ebuf int[NE] (csr ALIASES this)
  //   | h[NN*CC bf16]
  const size_t OFF_B  = 0;
  const size_t BH_B   = 400128;
  const size_t GC_B   = 401152;
  const size_t SCSH_B = 402176;
  const size_t WSW_B  = 403712;
  const size_t EB_B   = 436480;
  const size_t H_B    = EB_B + (size_t)NE * 4;        //  6,836,480
  const size_t NEED   = H_B + (size_t)NN * CC * 2;    // 32,436,480

  const int GGRID = (NN + GNB - 1) / GNB;  // 1563 blocks (no slicing)

  if (ws_size >= NEED) {
    int*   off   = (int*)((char*)d_ws + OFF_B);
    int*   bhist = (int*)((char*)d_ws + BH_B);
    int*   gcurz = (int*)((char*)d_ws + GC_B);
    float* scsh  = (float*)((char*)d_ws + SCSH_B);
    short* Wsw   = (short*)((char*)d_ws + WSW_B);
    int*   ebuf  = (int*)((char*)d_ws + EB_B);
    int*   csr   = ebuf;  // in-place (K3 reads segment fully before writing)
    short* h     = (short*)((char*)d_ws + H_B);

    hipMemsetAsync(bhist, 0, 2048, stream);  // bhist + gcurz
    prep_hist<<<ABLK, 256, 0, stream>>>(W, bias, gamma, beta, rmean, rvar,
                                        ei, Wsw, scsh, bhist);
    scatter_linear<<<ABLK + LBLK, 256, 0, stream>>>(
        ei, bhist, gcurz, ebuf, x, Wsw, scsh, h, ABLK);
    bucket_to_csr<<<NBUK, 1024, 0, stream>>>(ebuf, bhist, off, csr);
    gather_bn_relu<<<GGRID, 256, 0, stream>>>(h, off, csr, scsh, out);
  } else {
    int* cnt = (int*)d_ws;
    hipMemsetAsync(out, 0, (size_t)NN * CC * sizeof(float), stream);
    hipMemsetAsync(cnt, 0, (size_t)NN * sizeof(int), stream);
    edge_scatter<<<(NE * 32) / 256, 256, 0, stream>>>(x, ei, out, cnt);
    gemm_bn_relu_fb<<<(NN + 63) / 64, 256, 0, stream>>>(
        out, W, bias, gamma, beta, rmean, rvar, cnt);
  }
}

// Round 10
// 220.537 us; speedup vs baseline: 1.0133x; 1.0133x over previous
//
#include <hip/hip_runtime.h>

// GCN layer on MI355X — round 19: cache-line-padded atomic counters.
// r17 (K2 loads) and r18 (fusion tiering) were both NEUTRAL -> the ~140us
// invariant mass is in what never changed: ~100k global atomicAdds per
// kernel (K1->bhist, K2->gcurz) into a 1KB region = 16 cache lines.
// Same-line atomics serialize at the L2 slice (~10-50cy each) -> tens of us
// of tail in BOTH kernels, invisible in top-5 (<64us each). Fix: stride
// counters by 16 ints (64B line each) -> 256-way slice parallelism.
//   M1:  memsetAsync(bhist+gcurz, 0, 32KB)
//   K1 prep_hist:      Wsw swizzle + BN consts FUSED with bucket histogram
//                      (padded bhist)
//   K2 scatter_linear: bucket_scatter (padded gcurz) FUSED with linear_mfma
//   K3 bucket_to_csr:  1024 threads/block; csr ALIASES ebuf (in-place,
//                      r18-proven)
//   K4 gather_bn_relu: full-row e4xc16 dwordx4 (64.7us proven, untouched)
// mean(h[src]) = mean(x[src])@W + b (linearity); deg=0 -> sum=0 -> relu(sh).

#define NN 100000
#define NE 1600000
#define CC 128
#define BN_EPS 1e-5f
#define LBLK 1563     // ceil(NN/64) linear blocks
#define LSTR 136      // LDS row stride in bf16 (128 + 8 pad)
#define NBUK 256      // dst buckets
#define DPB 391       // dsts per bucket (256*391 = 100096 >= NN)
#define ACH 4096      // edges per scatter block
#define ABLK 391      // ceil(NE/ACH)
#define CAP 12288     // to_csr LDS segment capacity (mean 6250, +76 sigma)
#define GNB 64        // nodes per gather block
#define CAP2 1536     // gather csr LDS cap (mean 1024, sd 32: +16sigma)
#define BHS 16        // counter stride in ints (64B = one cache line)

typedef __attribute__((ext_vector_type(8))) short bf16x8;
typedef __attribute__((ext_vector_type(4))) float f32x4;

static __device__ __forceinline__ short f2bf(float f) {
  union { float f; unsigned u; } v; v.f = f;
  unsigned r = (v.u + 0x7FFF + ((v.u >> 16) & 1)) >> 16;  // RNE
  return (short)r;
}
static __device__ __forceinline__ float bflo(unsigned p) {
  return __uint_as_float(p << 16);
}
static __device__ __forceinline__ float bfhi(unsigned p) {
  return __uint_as_float(p & 0xffff0000u);
}

// 256-wide Hillis-Steele scan in LDS; leaves a[] exclusive, returns excl[t].
// (256-thread blocks only.)
static __device__ __forceinline__ int excl_scan256(int* a, int t, int v) {
  a[t] = v;
  __syncthreads();
  for (int d = 1; d < 256; d <<= 1) {
    const int x = (t >= d) ? a[t - d] : 0;
    __syncthreads();
    a[t] += x;
    __syncthreads();
  }
  const int incl = a[t];
  __syncthreads();
  a[t] = incl - v;
  __syncthreads();
  return incl - v;
}

// ---------------------------------------------------------------------------
// K1: prep (Wsw swizzle, col-permuted so D-lane m holds natural cols m*8..+7;
// BN scale/shift + bias) on blocks 0-63, bucket histogram on all 391 blocks.
// bhist (line-padded) pre-zeroed by the M1 memset.
// ---------------------------------------------------------------------------
__global__ __launch_bounds__(256) void prep_hist(
    const float* __restrict__ W, const float* __restrict__ bias,
    const float* __restrict__ gamma, const float* __restrict__ beta,
    const float* __restrict__ rmean, const float* __restrict__ rvar,
    const int* __restrict__ ei, short* __restrict__ Wsw,
    float* __restrict__ scsh, int* __restrict__ bhist) {
  __shared__ int lh[NBUK];
  const int t = threadIdx.x;
  const int i = blockIdx.x * 256 + t;
  if (i < CC * CC) {
    const int k = i >> 7, n = i & 127;
    const int nt = n & 7, m = n >> 3;
    const int kb = k >> 5, q = (k >> 3) & 3, j = k & 7;
    Wsw[(size_t)(((nt * 4 + kb) * 64 + (m + 16 * q)) * 8 + j)] = f2bf(W[i]);
  }
  if (i < CC) {
    const float sc = gamma[i] * rsqrtf(rvar[i] + BN_EPS);
    scsh[i] = sc;
    scsh[CC + i] = beta[i] - rmean[i] * sc;
    scsh[2 * CC + i] = bias[i];
  }
  lh[t] = 0;
  __syncthreads();
  const int e0 = blockIdx.x * ACH;
  const int e1 = min(NE, e0 + ACH);
  for (int e = e0 + t; e < e1; e += 256) atomicAdd(&lh[ei[NE + e] / DPB], 1);
  __syncthreads();
  if (lh[t]) atomicAdd(&bhist[t * BHS], lh[t]);  // one 64B line per counter
}

// ---------------------------------------------------------------------------
// K2: blocks [0,scat): bucket_scatter — chunk-sort 4096 edges by bucket in
// LDS, reserve contiguous global runs (line-padded gcurz atomics), write
// PACKED ebuf ((src<<9)|dstlocal) coalesced. blocks [scat,..): linear_mfma —
// h = bf16(x@W+b): x + Wsw staged in LDS, MFMA, direct row-major stores.
// Manual smem union: scatter 37.9KB | linear 49.4KB.
// ---------------------------------------------------------------------------
__global__ __launch_bounds__(256) void scatter_linear(
    const int* __restrict__ ei, const int* __restrict__ bhist,
    int* __restrict__ gcurz, int* __restrict__ ebuf,
    const float* __restrict__ x, const short* __restrict__ Wsw,
    const float* __restrict__ scsh, short* __restrict__ hout,
    int scat) {
  __shared__ __align__(16) char smem[50176];
  const int t = threadIdx.x;

  if (blockIdx.x < scat) {
    // ----- scatter role -----
    int2* sorted = (int2*)smem;                 // 32768
    int*  gsc    = (int*)(smem + 32768);        // +1024
    int*  lh     = (int*)(smem + 33792);
    int*  lex    = (int*)(smem + 34816);
    int*  rb     = (int*)(smem + 35840);
    int*  lc     = (int*)(smem + 36864);        // end 37888
    const int e0 = blockIdx.x * ACH;
    const int e1 = min(NE, e0 + ACH);
    const int gbase = excl_scan256(gsc, t, bhist[t * BHS]);
    lh[t] = 0;
    __syncthreads();
    for (int e = e0 + t; e < e1; e += 256) atomicAdd(&lh[ei[NE + e] / DPB], 1);
    __syncthreads();
    const int vh = lh[t];
    const int lbase = excl_scan256(lex, t, vh);
    lc[t] = lbase;
    if (vh > 0) rb[t] = gbase + atomicAdd(&gcurz[t * BHS], vh);
    __syncthreads();
    for (int e = e0 + t; e < e1; e += 256) {
      const int src = ei[e], dst = ei[NE + e];
      const int p = atomicAdd(&lc[dst / DPB], 1);
      sorted[p] = make_int2(src, dst);
    }
    __syncthreads();
    const int n = e1 - e0;
    for (int i = t; i < n; i += 256) {
      const int2 v = sorted[i];
      const int b = v.y / DPB;
      ebuf[rb[b] + (i - lex[b])] = (v.x << 9) | (v.y - b * DPB);
    }
    return;
  }

  // ----- linear role -----
  short* lsA = (short*)smem;            // 64*LSTR*2 = 17408
  short* lsW = (short*)(smem + 17408);  // 32768 -> end 50176
  const int n0 = (blockIdx.x - scat) * 64;

#pragma unroll
  for (int j = 0; j < 8; ++j) {
    const int idx = j * 256 + t;
    const int row = idx >> 5, kc4 = idx & 31;
    float4 v = make_float4(0.f, 0.f, 0.f, 0.f);
    if (n0 + row < NN) v = *(const float4*)(x + (size_t)(n0 + row) * CC + kc4 * 4);
    short4 sv;
    sv.x = f2bf(v.x); sv.y = f2bf(v.y); sv.z = f2bf(v.z); sv.w = f2bf(v.w);
    *(short4*)(lsA + row * LSTR + kc4 * 4) = sv;
  }
  // stage Wsw (32KB) once per block: 8 x bf16x8 per thread, coalesced
#pragma unroll
  for (int j = 0; j < 8; ++j) {
    const int idx = j * 256 + t;
    *(bf16x8*)(lsW + (size_t)idx * 8) = *(const bf16x8*)(Wsw + (size_t)idx * 8);
  }
  __syncthreads();

  const int wave = t >> 6, lane = t & 63;
  const int quad = lane >> 4, m = lane & 15;
  const int rowbase = n0 + wave * 16;

  f32x4 acc[8];
#pragma unroll
  for (int nt = 0; nt < 8; ++nt) acc[nt] = (f32x4){0.f, 0.f, 0.f, 0.f};

#pragma unroll
  for (int kb = 0; kb < 4; ++kb) {
    const bf16x8 a =
        *(const bf16x8*)(lsA + (wave * 16 + m) * LSTR + kb * 32 + quad * 8);
#pragma unroll
    for (int nt = 0; nt < 8; ++nt) {
      const bf16x8 bb = *(const bf16x8*)(lsW + (size_t)(((nt * 4 + kb) * 64 + lane) * 8));
      acc[nt] = __builtin_amdgcn_mfma_f32_16x16x32_bf16(a, bb, acc[nt], 0, 0, 0);
    }
  }

  const float4 b0 = *(const float4*)(scsh + 2 * CC + m * 8);
  const float4 b1 = *(const float4*)(scsh + 2 * CC + m * 8 + 4);
  const float bv[8] = {b0.x, b0.y, b0.z, b0.w, b1.x, b1.y, b1.z, b1.w};

#pragma unroll
  for (int reg = 0; reg < 4; ++reg) {
    const int R = rowbase + quad * 4 + reg;
    if (R >= NN) continue;
    bf16x8 hv;
#pragma unroll
    for (int nt = 0; nt < 8; ++nt) hv[nt] = f2bf(acc[nt][reg] + bv[nt]);
    *(bf16x8*)(hout + (size_t)R * CC + m * 8) = hv;
  }
}

// ---------------------------------------------------------------------------
// K3: one 1024-thread block per bucket, packed ebuf, padded bhist. csr MAY
// ALIAS ebuf: all reads of the block's segment complete before the copy-out
// writes; segments disjoint. seglen > CAP is +76sigma — cannot occur.
// ---------------------------------------------------------------------------
__global__ __launch_bounds__(1024) void bucket_to_csr(
    const int* __restrict__ ebuf, const int* __restrict__ bhist,
    int* __restrict__ off, int* __restrict__ csr) {
  __shared__ int gs[NBUK];
  __shared__ int dh[512];
  __shared__ int s[512];
  __shared__ int lcur[512];
  __shared__ int lcsr[CAP];  // 48 KB
  const int b = blockIdx.x, t = threadIdx.x;

  if (t < NBUK) gs[t] = bhist[t * BHS];
  __syncthreads();
  for (int d = 1; d < NBUK; d <<= 1) {
    int a0 = 0;
    if (t < NBUK && t >= d) a0 = gs[t - d];
    __syncthreads();
    if (t < NBUK) gs[t] += a0;
    __syncthreads();
  }
  const int seglen = bhist[b * BHS];
  const int segbase = gs[b] - seglen;
  const int lo = b * DPB;
  const int hi = min(NN, lo + DPB);
  const int nd = hi - lo;
  const int* eb = ebuf + segbase;

  if (t < 512) dh[t] = 0;
  __syncthreads();
  for (int i = t; i < seglen; i += 1024) atomicAdd(&dh[eb[i] & 511], 1);
  __syncthreads();

  if (t < 512) s[t] = dh[t];
  __syncthreads();
  for (int d = 1; d < 512; d <<= 1) {
    int a0 = 0;
    if (t < 512 && t >= d) a0 = s[t - d];
    __syncthreads();
    if (t < 512) s[t] += a0;
    __syncthreads();
  }
  if (t < 512) lcur[t] = s[t] - dh[t];  // exclusive
  if (t < nd) off[lo + t] = segbase + (s[t] - dh[t]);
  if (b == NBUK - 1 && t == 0) off[NN] = NE;
  __syncthreads();

  if (seglen <= CAP) {
    for (int i = t; i < seglen; i += 1024) {
      const int e = eb[i];
      const int p = atomicAdd(&lcur[e & 511], 1);
      lcsr[p] = (int)((unsigned)e >> 9);
    }
    __syncthreads();  // all segment reads done -> in-place write is safe
    for (int i = t; i < seglen; i += 1024) csr[segbase + i] = lcsr[i];
  } else {
    // unreachable for random inputs (+76 sigma); non-aliased-safe fallback
    for (int i = t; i < seglen; i += 1024) {
      const int e = eb[i];
      const int p = atomicAdd(&lcur[e & 511], 1);
      csr[segbase + p] = (int)((unsigned)e >> 9);
    }
  }
}

// ---------------------------------------------------------------------------
// K4: full-row e4xc16 gather (64.7us proven). Block = 64 nodes; loff + csr
// segment staged in LDS. Wave = one node at a time; lane = (e4 = lane>>4,
// c16 = lane&15). One dwordx4 = 4 edges x 256B rows; csr via ds_read;
// epilogue shfl_xor(16,32) + BN on e4==0 lanes.
// ---------------------------------------------------------------------------
__global__ __launch_bounds__(256) void gather_bn_relu(
    const short* __restrict__ h, const int* __restrict__ off,
    const int* __restrict__ csr, const float* __restrict__ scsh,
    float* __restrict__ out) {
  __shared__ int loff[GNB + 1];
  __shared__ int lcsr[CAP2];  // 6 KB
  const int nb0 = blockIdx.x * GNB;
  const int t = threadIdx.x;
  const int nnb = min(GNB, NN - nb0);

  for (int i = t; i <= nnb; i += 256) loff[i] = off[nb0 + i];
  __syncthreads();
  const int s0 = loff[0];
  const int seglen = loff[nnb] - s0;
  const int stg = min(seglen, CAP2);
  for (int i = t; i < stg; i += 256) lcsr[i] = csr[s0 + i];
  __syncthreads();

  const int wave = t >> 6, lane = t & 63;
  const int e4 = lane >> 4;    // edge slot 0..3
  const int c16 = lane & 15;   // col block: natural cols c16*8..+7
  const float4 sc0 = *(const float4*)(scsh + c16 * 8);
  const float4 sc1 = *(const float4*)(scsh + c16 * 8 + 4);
  const float4 sh0 = *(const float4*)(scsh + CC + c16 * 8);
  const float4 sh1 = *(const float4*)(scsh + CC + c16 * 8 + 4);

  const int lEnd = min(nnb, wave * 16 + 16);
  const bool inl = (seglen <= CAP2);
  for (int l = wave * 16; l < lEnd; ++l) {
    const int s = inl ? loff[l] - s0 : loff[l];
    const int e = inl ? loff[l + 1] - s0 : loff[l + 1];
    float a0 = 0.f, a1 = 0.f, a2 = 0.f, a3 = 0.f;
    float a4 = 0.f, a5 = 0.f, a6 = 0.f, a7 = 0.f;
    int i = s + e4;
    for (; i + 4 < e; i += 8) {
      const int q0 = inl ? lcsr[i] : csr[i];
      const int q1 = inl ? lcsr[i + 4] : csr[i + 4];
      const uint4 p0 = *(const uint4*)(h + (size_t)q0 * CC + c16 * 8);
      const uint4 p1 = *(const uint4*)(h + (size_t)q1 * CC + c16 * 8);
      a0 += bflo(p0.x) + bflo(p1.x); a1 += bfhi(p0.x) + bfhi(p1.x);
      a2 += bflo(p0.y) + bflo(p1.y); a3 += bfhi(p0.y) + bfhi(p1.y);
      a4 += bflo(p0.z) + bflo(p1.z); a5 += bfhi(p0.z) + bfhi(p1.z);
      a6 += bflo(p0.w) + bflo(p1.w); a7 += bfhi(p0.w) + bfhi(p1.w);
    }
    if (i < e) {
      const int q = inl ? lcsr[i] : csr[i];
      const uint4 p = *(const uint4*)(h + (size_t)q * CC + c16 * 8);
      a0 += bflo(p.x); a1 += bfhi(p.x);
      a2 += bflo(p.y); a3 += bfhi(p.y);
      a4 += bflo(p.z); a5 += bfhi(p.z);
      a6 += bflo(p.w); a7 += bfhi(p.w);
    }
    // reduce across the 4 e4 groups (lane bits 4,5)
    a0 += __shfl_xor(a0, 16); a1 += __shfl_xor(a1, 16);
    a2 += __shfl_xor(a2, 16); a3 += __shfl_xor(a3, 16);
    a4 += __shfl_xor(a4, 16); a5 += __shfl_xor(a5, 16);
    a6 += __shfl_xor(a6, 16); a7 += __shfl_xor(a7, 16);
    a0 += __shfl_xor(a0, 32); a1 += __shfl_xor(a1, 32);
    a2 += __shfl_xor(a2, 32); a3 += __shfl_xor(a3, 32);
    a4 += __shfl_xor(a4, 32); a5 += __shfl_xor(a5, 32);
    a6 += __shfl_xor(a6, 32); a7 += __shfl_xor(a7, 32);
    if (e4 == 0) {
      const float inv = (e > s) ? 1.0f / (float)(e - s) : 0.0f;
      float4 o0, o1;
      o0.x = fmaxf(0.f, a0 * inv * sc0.x + sh0.x);
      o0.y = fmaxf(0.f, a1 * inv * sc0.y + sh0.y);
      o0.z = fmaxf(0.f, a2 * inv * sc0.z + sh0.z);
      o0.w = fmaxf(0.f, a3 * inv * sc0.w + sh0.w);
      o1.x = fmaxf(0.f, a4 * inv * sc1.x + sh1.x);
      o1.y = fmaxf(0.f, a5 * inv * sc1.y + sh1.y);
      o1.z = fmaxf(0.f, a6 * inv * sc1.z + sh1.z);
      o1.w = fmaxf(0.f, a7 * inv * sc1.w + sh1.w);
      float* op = out + (size_t)(nb0 + l) * CC + c16 * 8;
      *(float4*)op = o0;
      *(float4*)(op + 4) = o1;
    }
  }
}

// ---------------------------------------------------------------------------
// Fallback (small ws): atomic scatter + fp32 vector GEMM.
// ---------------------------------------------------------------------------
__global__ __launch_bounds__(256) void edge_scatter(
    const float* __restrict__ x, const int* __restrict__ ei,
    float* __restrict__ sums, int* __restrict__ cnt) {
  int gt = blockIdx.x * 256 + threadIdx.x;
  int e = gt >> 5;
  int sub = gt & 31;
  if (e >= NE) return;
  int src = ei[e];
  int dst = ei[NE + e];
  const float4 v = *(const float4*)(x + (size_t)src * CC + sub * 4);
  float* o = sums + (size_t)dst * CC + sub * 4;
  unsafeAtomicAdd(o + 0, v.x);
  unsafeAtomicAdd(o + 1, v.y);
  unsafeAtomicAdd(o + 2, v.z);
  unsafeAtomicAdd(o + 3, v.w);
  if (sub == 0) atomicAdd(cnt + dst, 1);
}

__global__ __launch_bounds__(256) void gemm_bn_relu_fb(
    float* buf, const float* __restrict__ W, const float* __restrict__ bias,
    const float* __restrict__ gamma, const float* __restrict__ beta,
    const float* __restrict__ rmean, const float* __restrict__ rvar,
    const int* __restrict__ cnt) {
  __shared__ float xsT[CC][65];
  const int t = threadIdx.x;
  const int n0 = blockIdx.x * 64;
  for (int j = 0; j < 8; ++j) {
    int i = t + 256 * j;
    int row = i >> 5;
    int ko = (i & 31) * 4;
    float4 v = make_float4(0.f, 0.f, 0.f, 0.f);
    if (n0 + row < NN) v = *(const float4*)(buf + (size_t)(n0 + row) * CC + ko);
    xsT[ko + 0][row] = v.x;
    xsT[ko + 1][row] = v.y;
    xsT[ko + 2][row] = v.z;
    xsT[ko + 3][row] = v.w;
  }
  __syncthreads();
  const int cg = t & 31;
  const int ng8 = (t >> 5) * 8;
  float acc[8][4];
#pragma unroll
  for (int j = 0; j < 8; ++j)
#pragma unroll
    for (int c = 0; c < 4; ++c) acc[j][c] = 0.f;
#pragma unroll 8
  for (int k = 0; k < CC; ++k) {
    const float4 wv = *(const float4*)(W + k * CC + cg * 4);
#pragma unroll
    for (int j = 0; j < 8; ++j) {
      const float xv = xsT[k][ng8 + j];
      acc[j][0] = fmaf(xv, wv.x, acc[j][0]);
      acc[j][1] = fmaf(xv, wv.y, acc[j][1]);
      acc[j][2] = fmaf(xv, wv.z, acc[j][2]);
      acc[j][3] = fmaf(xv, wv.w, acc[j][3]);
    }
  }
  const float4 bb = *(const float4*)(bias + cg * 4);
  const float4 gg = *(const float4*)(gamma + cg * 4);
  const float4 bt = *(const float4*)(beta + cg * 4);
  const float4 mu = *(const float4*)(rmean + cg * 4);
  const float4 vr = *(const float4*)(rvar + cg * 4);
  float sc[4], sh[4];
  sc[0] = gg.x * rsqrtf(vr.x + BN_EPS);
  sc[1] = gg.y * rsqrtf(vr.y + BN_EPS);
  sc[2] = gg.z * rsqrtf(vr.z + BN_EPS);
  sc[3] = gg.w * rsqrtf(vr.w + BN_EPS);
  sh[0] = bt.x - mu.x * sc[0];
  sh[1] = bt.y - mu.y * sc[1];
  sh[2] = bt.z - mu.z * sc[2];
  sh[3] = bt.w - mu.w * sc[3];
#pragma unroll
  for (int j = 0; j < 8; ++j) {
    const int n = n0 + ng8 + j;
    if (n >= NN) continue;
    const int cn = cnt[n];
    const float inv = cn > 0 ? 1.0f / (float)cn : 0.0f;
    const float bsel = cn > 0 ? 1.0f : 0.0f;
    float4 o;
    o.x = fmaxf(0.f, (acc[j][0] * inv + bsel * bb.x) * sc[0] + sh[0]);
    o.y = fmaxf(0.f, (acc[j][1] * inv + bsel * bb.y) * sc[1] + sh[1]);
    o.z = fmaxf(0.f, (acc[j][2] * inv + bsel * bb.z) * sc[2] + sh[2]);
    o.w = fmaxf(0.f, (acc[j][3] * inv + bsel * bb.w) * sc[3] + sh[3]);
    *(float4*)(buf + (size_t)n * CC + cg * 4) = o;
  }
}

extern "C" void kernel_launch(void* const* d_in, const int* in_sizes, int n_in,
                              void* d_out, int out_size, void* d_ws, size_t ws_size,
                              hipStream_t stream) {
  const float* x     = (const float*)d_in[0];
  const int*   ei    = (const int*)d_in[1];
  const float* W     = (const float*)d_in[2];
  const float* bias  = (const float*)d_in[3];
  const float* gamma = (const float*)d_in[4];
  const float* beta  = (const float*)d_in[5];
  const float* rmean = (const float*)d_in[6];
  const float* rvar  = (const float*)d_in[7];
  float* out = (float*)d_out;

  // ws layout (bytes):
  //   off[NN+1] | bhist[256*16] | gcurz[256*16] (contig -> one 32KB memset)
  //   | scsh[384f] | Wsw[16384 bf16] | ebuf int[NE] (csr ALIASES this)
  //   | h[NN*CC bf16]
  const size_t OFF_B  = 0;
  const size_t BH_B   = 400128;
  const size_t GC_B   = BH_B + 16384;                 // 416512
  const size_t SCSH_B = GC_B + 16384;                 // 432896
  const size_t WSW_B  = SCSH_B + 1536;                // 434432
  const size_t EB_B   = WSW_B + 32768;                // 467200
  const size_t H_B    = EB_B + (size_t)NE * 4;        //  6,867,200
  const size_t NEED   = H_B + (size_t)NN * CC * 2;    // 32,467,200

  const int GGRID = (NN + GNB - 1) / GNB;  // 1563 blocks (no slicing)

  if (ws_size >= NEED) {
    int*   off   = (int*)((char*)d_ws + OFF_B);
    int*   bhist = (int*)((char*)d_ws + BH_B);
    int*   gcurz = (int*)((char*)d_ws + GC_B);
    float* scsh  = (float*)((char*)d_ws + SCSH_B);
    short* Wsw   = (short*)((char*)d_ws + WSW_B);
    int*   ebuf  = (int*)((char*)d_ws + EB_B);
    int*   csr   = ebuf;  // in-place (K3 reads segment fully before writing)
    short* h     = (short*)((char*)d_ws + H_B);

    hipMemsetAsync(bhist, 0, 32768, stream);  // bhist + gcurz (padded)
    prep_hist<<<ABLK, 256, 0, stream>>>(W, bias, gamma, beta, rmean, rvar,
                                        ei, Wsw, scsh, bhist);
    scatter_linear<<<ABLK + LBLK, 256, 0, stream>>>(
        ei, bhist, gcurz, ebuf, x, Wsw, scsh, h, ABLK);
    bucket_to_csr<<<NBUK, 1024, 0, stream>>>(ebuf, bhist, off, csr);
    gather_bn_relu<<<GGRID, 256, 0, stream>>>(h, off, csr, scsh, out);
  } else {
    int* cnt = (int*)d_ws;
    hipMemsetAsync(out, 0, (size_t)NN * CC * sizeof(float), stream);
    hipMemsetAsync(cnt, 0, (size_t)NN * sizeof(int), stream);
    edge_scatter<<<(NE * 32) / 256, 256, 0, stream>>>(x, ei, out, cnt);
    gemm_bn_relu_fb<<<(NN + 63) / 64, 256, 0, stream>>>(
        out, W, bias, gamma, beta, rmean, rvar, cnt);
  }
}